// Round 7
// baseline (17958.653 us; speedup 1.0000x reference)
//
#include <hip/hip_runtime.h>

typedef __attribute__((ext_vector_type(8))) short short8;
typedef __attribute__((ext_vector_type(4))) float f32x4;
typedef __attribute__((ext_vector_type(4))) unsigned uint32x4;

#define SEQ 4096
#define HID 2048
#define G4  8192
#define NBLK 256

static __device__ __forceinline__ ushort f2bf(float f) {
    unsigned u = __float_as_uint(f);
    u = (u + 0x7fffu + ((u >> 16) & 1u)) >> 16;   // RNE
    return (ushort)u;
}
static __device__ __forceinline__ float bf_lo(unsigned x) { return __uint_as_float(x << 16); }
static __device__ __forceinline__ float bf_hi(unsigned x) { return __uint_as_float(x & 0xffff0000u); }

// Publish one {f32 h (lo), u32 tag (hi)} u64 at the device coherence point.
static __device__ __forceinline__ void atomic_pub_u64(unsigned long long* p,
                                                      unsigned long long v) {
    unsigned long long ap = (unsigned long long)p;
    asm volatile("global_atomic_swap_x2 %0, %1, off" :: "v"(ap), "v"(v) : "memory");
}

// 32 B coherent read (two dwordx4, sc0 sc1 bypass local caches), one waitcnt.
static __device__ __forceinline__ void load_slot8(const unsigned long long* p,
                                                  uint32x4& a, uint32x4& b) {
    unsigned long long ap = (unsigned long long)p;
    asm volatile("global_load_dwordx4 %0, %2, off sc0 sc1\n\t"
                 "global_load_dwordx4 %1, %2, off offset:16 sc0 sc1\n\t"
                 "s_waitcnt vmcnt(0)"
                 : "=&v"(a), "=&v"(b) : "v"(ap) : "memory");
}

// h_lds address map: +4 floats pad per 32 floats -> reads <=2-way bank aliased
static __device__ __forceinline__ int hmap(int col) { return col + ((col >> 5) << 2); }

// ---------------- f32 -> bf16 conversion (vectorized, 4 elems/thread) ----------
__global__ void __launch_bounds__(256) k_f32_to_bf16(const float* __restrict__ in,
                                                     ushort* __restrict__ out, int n4) {
    int i = blockIdx.x * blockDim.x + threadIdx.x;
    if (i < n4) {
        float4 v = ((const float4*)in)[i];
        ushort4 o;
        o.x = f2bf(v.x); o.y = f2bf(v.y); o.z = f2bf(v.z); o.w = f2bf(v.w);
        ((ushort4*)out)[i] = o;
    }
}

// ---------------- xg = x @ W_ih^T + (b_ih + b_hh), bf16 MFMA, 128x128 tile ------
__global__ void __launch_bounds__(256) k_gemm_xg(
    const ushort* __restrict__ A, const ushort* __restrict__ B,
    const float* __restrict__ bih, const float* __restrict__ bhh,
    float* __restrict__ C)
{
    __shared__ ushort Asm[128 * 40];
    __shared__ ushort Bsm[128 * 40];
    const int tid = threadIdx.x;
    const int brow = blockIdx.y * 128;
    const int bcol = blockIdx.x * 128;
    const int w = tid >> 6, l = tid & 63;
    const int wm = w >> 1, wn = w & 1;

    f32x4 acc[4][4] = {};

    for (int k0 = 0; k0 < 2048; k0 += 32) {
        __syncthreads();
        #pragma unroll
        for (int i = 0; i < 2; ++i) {
            int q = tid + i * 256;
            int r = q >> 2, kc = q & 3;
            *(uint4*)((char*)Asm + r * 80 + kc * 16) =
                *(const uint4*)(A + (size_t)(brow + r) * 2048 + k0 + kc * 8);
            *(uint4*)((char*)Bsm + r * 80 + kc * 16) =
                *(const uint4*)(B + (size_t)(bcol + r) * 2048 + k0 + kc * 8);
        }
        __syncthreads();

        short8 af[4], bf[4];
        #pragma unroll
        for (int m = 0; m < 4; ++m)
            af[m] = *(const short8*)((char*)Asm + (wm * 64 + m * 16 + (l & 15)) * 80 + (l >> 4) * 16);
        #pragma unroll
        for (int n = 0; n < 4; ++n)
            bf[n] = *(const short8*)((char*)Bsm + (wn * 64 + n * 16 + (l & 15)) * 80 + (l >> 4) * 16);

        #pragma unroll
        for (int m = 0; m < 4; ++m)
            #pragma unroll
            for (int n = 0; n < 4; ++n)
                acc[m][n] = __builtin_amdgcn_mfma_f32_16x16x32_bf16(af[m], bf[n], acc[m][n], 0, 0, 0);
    }

    const int lr = (l >> 4) * 4, lc = l & 15;
    #pragma unroll
    for (int m = 0; m < 4; ++m)
        #pragma unroll
        for (int n = 0; n < 4; ++n) {
            int col = bcol + wn * 64 + n * 16 + lc;
            float bsum = bih[col] + bhh[col];
            #pragma unroll
            for (int r = 0; r < 4; ++r) {
                int rowg = brow + wm * 64 + m * 16 + lr + r;
                C[(size_t)rowg * 8192 + col] = acc[m][n][r] + bsum;
            }
        }
}

// ---------------- persistent cooperative LSTM recurrence ------------------------
// 256 blocks x 512 threads. Wave u (0..7) owns hidden unit hbase+u; lane =
// (gate g 0..3) x (col-chunk cc 0..15). W_hh slice pre-expanded f32 in
// registers. Cross-block exchange: PARITY DOUBLE-BUFFERED tagged slots.
//   publish h_{t+1} (tag t+1)  -> buf[(t+1)&1]
//   poll at step t reads          buf[t&1], waits tag == t
// Deadlock-free: buf[p] tag t is only overwritten (with t+2) by a block that
// passed step t+1's poll, which requires ALL blocks published t+1, which they
// do only AFTER all their step-t reads of buf[p] completed (reads precede
// barrier [A]; publish follows it). So equality polling can never miss.
__global__ void __launch_bounds__(512, 1) k_lstm_rec(
    const ushort* __restrict__ Whh,          // bf16 [8192][2048]
    const float* __restrict__ xg,            // [4096][8192]
    unsigned long long* __restrict__ hslot,  // [2][2048] {h,tag}, 0xFF-memset
    const float* __restrict__ Wlin,          // [2048]
    const float* __restrict__ blin,          // [1]
    float* __restrict__ out)                 // [1]
{
    extern __shared__ char smem[];
    float* h_lds = (float*)smem;             // hmap(2044)+4 ~ 2304 f32 = 9216 B
    float* r_lds = (float*)(smem + 9216);    // 8 f32 reduction scratch

    const int tid = threadIdx.x;
    const int b   = blockIdx.x;
    const int hbase = b * 8;
    const int u  = tid >> 6;        // wave id = local hidden unit
    const int g  = (tid >> 4) & 3;  // gate (torch order i,f,g,o)
    const int cc = tid & 15;        // col-chunk

    // one-time: stage + expand this thread's W row slice to f32 registers
    // row = g*2048 + hbase + u, cols cc*8 + k*128 + j (j=0..7, k=0..15)
    f32x4 wf[32];
    {
        const ushort* wr = Whh + (size_t)((g << 11) + hbase + u) * 2048 + (cc << 3);
        #pragma unroll
        for (int k = 0; k < 16; ++k) {
            uint4 wv = *(const uint4*)(wr + (k << 7));
            wf[2 * k]     = (f32x4){bf_lo(wv.x), bf_hi(wv.x), bf_lo(wv.y), bf_hi(wv.y)};
            wf[2 * k + 1] = (f32x4){bf_lo(wv.z), bf_hi(wv.z), bf_lo(wv.w), bf_hi(wv.w)};
        }
    }

    float c_reg = 0.0f;   // redundant across all 64 lanes of the wave

    // publish h_0 = 0 with tag 0 into buf[0]
    if (tid < 8)
        atomic_pub_u64(&hslot[hbase + tid], 0ull);

    for (int t = 0; t < SEQ; ++t) {
        const unsigned long long* src = hslot + (size_t)(t & 1) * HID;
        unsigned long long*       dst = hslot + (size_t)((t + 1) & 1) * HID;

        // xg gate preact for (g, u): same addr across the 16 cc lanes (bcast).
        float xgv = xg[(size_t)t * G4 + (g << 11) + hbase + u];

        // poll own 4 slots of buf[t&1] until tags == t, stage h into LDS
        {
            const unsigned tgt = (unsigned)t;
            uint32x4 a, bq;
            int spin = 0;
            while (true) {
                load_slot8(src + tid * 4, a, bq);
                if (a.y == tgt && a.w == tgt && bq.y == tgt && bq.w == tgt) break;
                if ((++spin & 63) == 0) {
                    // escape hatch (proven R5): acquire emits inv if sc0sc1
                    // loads were ever stale; never taken on the fast path
                    unsigned d = __hip_atomic_load((const unsigned*)src,
                                                   __ATOMIC_ACQUIRE, __HIP_MEMORY_SCOPE_AGENT);
                    asm volatile("" :: "v"(d));
                } else {
                    __builtin_amdgcn_s_sleep(2);
                }
            }
            *(f32x4*)(h_lds + hmap(tid * 4)) =
                (f32x4){__uint_as_float(a.x), __uint_as_float(a.z),
                        __uint_as_float(bq.x), __uint_as_float(bq.z)};
        }
        __syncthreads();   // [A] h_t staged; all reads of buf[t&1] complete

        // dot: pure f32 FMA, W from registers, h from LDS (4 indep chains)
        float s0 = 0.f, s1 = 0.f, s2 = 0.f, s3 = 0.f;
        #pragma unroll
        for (int k = 0; k < 16; ++k) {
            int col0 = (cc << 3) + (k << 7);
            const float* hp = h_lds + hmap(col0);
            f32x4 ha = *(const f32x4*)hp;
            f32x4 hb = *(const f32x4*)(hp + 4);
            f32x4 wa = wf[2 * k], wb = wf[2 * k + 1];
            s0 += wa.x * ha.x;  s1 += wa.y * ha.y;
            s2 += wa.z * ha.z;  s3 += wa.w * ha.w;
            s0 += wb.x * hb.x;  s1 += wb.y * hb.y;
            s2 += wb.z * hb.z;  s3 += wb.w * hb.w;
        }
        float sum = (s0 + s1) + (s2 + s3);
        // reduce over the 16 cc lanes (intra-wave)
        sum += __shfl_xor(sum, 1);
        sum += __shfl_xor(sum, 2);
        sum += __shfl_xor(sum, 4);
        sum += __shfl_xor(sum, 8);
        sum += xgv;   // full gate preactivation, replicated on all 16 lanes

        // gather the 4 gate totals (lane groups 0-15,16-31,32-47,48-63)
        float gi = __shfl(sum, 0);
        float gf = __shfl(sum, 16);
        float gg = __shfl(sum, 32);
        float go = __shfl(sum, 48);

        // gates computed redundantly on all lanes; c_reg stays consistent
        float si = 1.0f / (1.0f + __expf(-gi));
        float sf = 1.0f / (1.0f + __expf(-gf));
        float tg = tanhf(gg);
        float so = 1.0f / (1.0f + __expf(-go));
        c_reg = sf * c_reg + si * tg;
        float hn = so * tanhf(c_reg);

        // publish immediately (per wave) into the OTHER parity buffer — safe
        // with double buffering (see header proof)
        if ((tid & 63) == 0) {
            unsigned long long pv =
                ((unsigned long long)(unsigned)(t + 1) << 32) |
                (unsigned long long)__float_as_uint(hn);
            atomic_pub_u64(&dst[hbase + u], pv);
        }
        __syncthreads();   // [B] protect h_lds from next-iteration staging
    }

    // final: out = sigmoid(h_SEQ . W_lin + b_lin), block 0 only
    // h_SEQ carries tag SEQ in buf[SEQ&1] = buf[0]
    if (b == 0) {
        const unsigned tgt = (unsigned)SEQ;
        uint32x4 a, bq;
        int spin = 0;
        while (true) {
            load_slot8(hslot + tid * 4, a, bq);
            if (a.y == tgt && a.w == tgt && bq.y == tgt && bq.w == tgt) break;
            if ((++spin & 63) == 0) {
                unsigned d = __hip_atomic_load((const unsigned*)hslot,
                                               __ATOMIC_ACQUIRE, __HIP_MEMORY_SCOPE_AGENT);
                asm volatile("" :: "v"(d));
            } else {
                __builtin_amdgcn_s_sleep(2);
            }
        }
        const float* wl = Wlin + tid * 4;
        float s = __uint_as_float(a.x)  * wl[0] + __uint_as_float(a.z)  * wl[1]
                + __uint_as_float(bq.x) * wl[2] + __uint_as_float(bq.z) * wl[3];
        #pragma unroll
        for (int o = 1; o < 64; o <<= 1) s += __shfl_xor(s, o);
        if ((tid & 63) == 0) r_lds[u] = s;
        __syncthreads();
        if (tid == 0) {
            float tot = r_lds[0] + r_lds[1] + r_lds[2] + r_lds[3]
                      + r_lds[4] + r_lds[5] + r_lds[6] + r_lds[7] + blin[0];
            out[0] = 1.0f / (1.0f + __expf(-tot));
        }
    }
}

extern "C" void kernel_launch(void* const* d_in, const int* in_sizes, int n_in,
                              void* d_out, int out_size, void* d_ws, size_t ws_size,
                              hipStream_t stream) {
    const float* x    = (const float*)d_in[0];   // [1][4096][2048]
    const float* Wih  = (const float*)d_in[1];   // [8192][2048]
    const float* Whh  = (const float*)d_in[2];   // [8192][2048]
    const float* bih  = (const float*)d_in[3];   // [8192]
    const float* bhh  = (const float*)d_in[4];   // [8192]
    const float* Wlin = (const float*)d_in[5];   // [1][2048]
    const float* blin = (const float*)d_in[6];   // [1]
    float* out = (float*)d_out;

    char* ws = (char*)d_ws;
    float*              xgbuf = (float*)ws;                        // 134,217,728 B
    ushort*             xbf   = (ushort*)(ws + 134217728);         //  16,777,216 B
    ushort*             wihbf = (ushort*)(ws + 150994944);         //  33,554,432 B
    ushort*             whhbf = (ushort*)(ws + 184549376);         //  33,554,432 B
    unsigned long long* hslot = (unsigned long long*)(ws + 218103808); // 32,768 B (2x2048)

    // f32 -> bf16 (x, W_ih, W_hh)
    k_f32_to_bf16<<<8192,  256, 0, stream>>>(x,   xbf,   2097152);
    k_f32_to_bf16<<<16384, 256, 0, stream>>>(Wih, wihbf, 4194304);
    k_f32_to_bf16<<<16384, 256, 0, stream>>>(Whh, whhbf, 4194304);

    // input GEMM: all timesteps' input-side gate preactivations
    k_gemm_xg<<<dim3(64, 32), 256, 0, stream>>>(xbf, wihbf, bih, bhh, xgbuf);

    // invalidate BOTH parity buffers every call (tags 0..SEQ never match 0xFF)
    hipMemsetAsync(hslot, 0xFF, 2 * HID * sizeof(unsigned long long), stream);

    // persistent cooperative recurrence: launch config identical to Round 5
    hipFuncSetAttribute((const void*)k_lstm_rec,
                        hipFuncAttributeMaxDynamicSharedMemorySize, 163840);
    void* args[] = { (void*)&whhbf, (void*)&xgbuf, (void*)&hslot,
                     (void*)&Wlin, (void*)&blin, (void*)&out };
    hipLaunchCooperativeKernel((const void*)k_lstm_rec, dim3(NBLK), dim3(512),
                               args, 139520, stream);
}